// Round 6
// baseline (272.841 us; speedup 1.0000x reference)
//
#include <hip/hip_runtime.h>

#define HIDDEN 128
#define P_NUM 8
#define PLEN 4
#define ETYPES 2
#define BN 32                      // nodes per block (100000 = 3125*32, no tail)
#define APAD 8
#define AROW (2*HIDDEN + APAD)     // 264 bf16

typedef __attribute__((ext_vector_type(8))) short short8;
typedef __attribute__((ext_vector_type(4))) float floatx4;
typedef __attribute__((address_space(1))) const unsigned int gu32;
typedef __attribute__((address_space(3))) unsigned int lu32;

// counted vmcnt wait: memory clobber pins surrounding loads; sched_barrier after (rule #18)
#define WAITV(n) do { asm volatile("s_waitcnt vmcnt(" #n ")" ::: "memory"); \
                      __builtin_amdgcn_sched_barrier(0); } while (0)

__device__ __forceinline__ unsigned short f2bf(float x) {
  unsigned int u = __float_as_uint(x);
  u += 0x7FFFu + ((u >> 16) & 1u);
  return (unsigned short)(u >> 16);
}

// generic f32 -> bf16 (used for W_fc)
__global__ __launch_bounds__(256) void cvt_bf16(const float* __restrict__ in,
                                                unsigned short* __restrict__ out, int n4) {
  int i = blockIdx.x * blockDim.x + threadIdx.x;
  if (i < n4) {
    float4 f = ((const float4*)in)[i];
    ((ushort4*)out)[i] = make_ushort4(f2bf(f.x), f2bf(f.y), f2bf(f.z), f2bf(f.w));
  }
}

// feats f32 -> BIASED u8 (u = rint(x*127/absmax)+128) with per-row scale.
__global__ __launch_bounds__(256) void cvt_u8(const float* __restrict__ in,
                                              unsigned char* __restrict__ q,
                                              float* __restrict__ scales, int n_rows) {
  const int wavei = blockIdx.x * 4 + (threadIdx.x >> 6);
  const int lane = threadIdx.x & 63;
  const int row = wavei * 2 + (lane >> 5);
  const int l32 = lane & 31;
  if (row >= n_rows) return;
  float4 f = *(const float4*)(in + (size_t)row * HIDDEN + l32 * 4);
  float m = fmaxf(fmaxf(fabsf(f.x), fabsf(f.y)), fmaxf(fabsf(f.z), fabsf(f.w)));
  #pragma unroll
  for (int d = 1; d < 32; d <<= 1) m = fmaxf(m, __shfl_xor(m, d));
  float inv = (m > 0.f) ? 127.f / m : 0.f;
  int q0 = (int)rintf(f.x * inv) + 128, q1 = (int)rintf(f.y * inv) + 128;
  int q2 = (int)rintf(f.z * inv) + 128, q3 = (int)rintf(f.w * inv) + 128;
  unsigned int pack = (q0 & 0xFF) | ((q1 & 0xFF) << 8) | ((q2 & 0xFF) << 16) | ((q3 & 0xFF) << 24);
  ((unsigned int*)q)[(size_t)row * (HIDDEN / 4) + l32] = pack;
  if (l32 == 0) scales[row] = m / 127.f;
}

// Fused: type-specialized-wave gather staged through LDS via global_load_lds,
// depth-2 software pipeline with hand-counted vmcnt (never 0 in the loop),
// then in-block MFMA GEMM. Wave-private staging buffers -> no barriers in pipeline.
__global__ __launch_bounds__(256, 3) void impeller_fused(
    const unsigned char* __restrict__ feats_q,  // biased u8, N x 128
    const float* __restrict__ scales,           // f32, N
    const int* __restrict__ paths,
    const int* __restrict__ ptypes,
    const float* __restrict__ pweights,
    const unsigned short* __restrict__ wfc_bf,  // bf16, 128 x 256
    float* __restrict__ out,
    int n_nodes)
{
  __shared__ __align__(16) unsigned short A[BN * AROW];      // 16896 B
  __shared__ __align__(16) unsigned char GB[4][2][4096];     // 32768 B: per-wave dbuf staging

  const int tid = threadIdx.x;
  const int n0 = blockIdx.x * BN;
  const int wv = tid >> 6;
  const int lane = tid & 63;
  const int g = lane >> 4;          // group 0..3 (one path slot per group)
  const int r = lane & 15;          // dims [r*8, r*8+8)

  const int e = wv >> 1;            // this wave's edge type
  const int nh = (wv & 1) * 16;     // local node half: nh..nh+15

  // ---- this group's path(s) of type e ----
  int p0 = 0, p1 = 0, cnt = 0;
  #pragma unroll
  for (int p = 0; p < P_NUM; ++p) {
    const int t = ptypes[p];
    if (t == e) { if (cnt == g) p0 = p; if (cnt == g + 4) p1 = p; ++cnt; }
  }
  const bool v0 = (g < cnt);
  const float ic = (cnt > 0) ? 1.f / (float)cnt : 0.f;
  float cl0[PLEN];
  #pragma unroll
  for (int l = 0; l < PLEN; ++l) {
    const float w = pweights[e * PLEN + l] * ic;
    cl0[l] = v0 ? w : 0.f;
  }
  if (!v0) p0 = 0;

  const int* pbase = paths + (size_t)p0 * n_nodes * PLEN;
  const int nodebase = n0 + nh;

  if (cnt <= 4) {
    // ================= fast path: LDS-staged counted-vmcnt pipeline =================
    unsigned char* gb0 = &GB[wv][0][0];
    const int byteoff = (lane & 7) * 16;            // lane's 16B within its row
    const bool rsel = ((lane >> 3) & 1) != 0;       // which of the 2 rows in this gld_lds

    // one gld_lds = 8 random 128B rows (8 groups x 8 lanes x 16B) -> 1KB LDS
    auto ISSUE_ROWS = [&](int s, const int4& iA, const int4& iB) {
      unsigned char* buf = gb0 + (s & 1) * 4096;
      const int i0 = rsel ? iA.y : iA.x;    // node A, hops 0/1
      __builtin_amdgcn_global_load_lds((gu32*)(feats_q + (size_t)(unsigned)i0 * HIDDEN + byteoff),
                                       (lu32*)(buf), 16, 0, 0);
      const int i1 = rsel ? iA.w : iA.z;    // node A, hops 2/3
      __builtin_amdgcn_global_load_lds((gu32*)(feats_q + (size_t)(unsigned)i1 * HIDDEN + byteoff),
                                       (lu32*)(buf + 1024), 16, 0, 0);
      const int i2 = rsel ? iB.y : iB.x;    // node B, hops 0/1
      __builtin_amdgcn_global_load_lds((gu32*)(feats_q + (size_t)(unsigned)i2 * HIDDEN + byteoff),
                                       (lu32*)(buf + 2048), 16, 0, 0);
      const int i3 = rsel ? iB.w : iB.z;    // node B, hops 2/3
      __builtin_amdgcn_global_load_lds((gu32*)(feats_q + (size_t)(unsigned)i3 * HIDDEN + byteoff),
                                       (lu32*)(buf + 3072), 16, 0, 0);
    };
    auto CONSUME = [&](int s, const float (&sa)[4], const float (&sb)[4]) {
      const unsigned char* buf = gb0 + (s & 1) * 4096;
      #pragma unroll
      for (int X = 0; X < 2; ++X) {
        const unsigned char* nb = buf + X * 2048;
        float a[8] = {0.f, 0.f, 0.f, 0.f, 0.f, 0.f, 0.f, 0.f};
        float corr = 0.f;
        #pragma unroll
        for (int l = 0; l < PLEN; ++l) {
          // row slot for (g, hop l): written by instr m=l>>1 at row 2g+(l&1)
          const uint2 f = *(const uint2*)(nb + (l >> 1) * 1024 + (2 * g + (l & 1)) * 128 + r * 8);
          const float cs = cl0[l] * (X ? sb[l] : sa[l]);
          corr += cs;
          a[0] += cs * (float)( f.x        & 0xFFu);
          a[1] += cs * (float)((f.x >>  8) & 0xFFu);
          a[2] += cs * (float)((f.x >> 16) & 0xFFu);
          a[3] += cs * (float)( f.x >> 24        );
          a[4] += cs * (float)( f.y        & 0xFFu);
          a[5] += cs * (float)((f.y >>  8) & 0xFFu);
          a[6] += cs * (float)((f.y >> 16) & 0xFFu);
          a[7] += cs * (float)( f.y >> 24        );
        }
        #pragma unroll
        for (int k = 0; k < 8; ++k) {
          a[k] += __shfl_xor(a[k], 16);
          a[k] += __shfl_xor(a[k], 32);
        }
        corr += __shfl_xor(corr, 16);
        corr += __shfl_xor(corr, 32);
        const float c128 = 128.f * corr;
        if (g == 0) {
          short8 u;
          #pragma unroll
          for (int k = 0; k < 8; ++k) u[k] = (short)f2bf(a[k] - c128);
          *(short8*)&A[(nh + s * 2 + X) * AROW + e * HIDDEN + r * 8] = u;
        }
      }
    };

    int4 aC, bC, aN, bN;
    float sc_a[4], sc_b[4], sn_a[4], sn_b[4];

    // prologue: idx(0), idx(1); wait idx(0); rows(0)+scales(0)
    {
      const int nn0 = nodebase;
      aC = *(const int4*)&pbase[(size_t)nn0 * PLEN];
      bC = *(const int4*)&pbase[(size_t)(nn0 + 1) * PLEN];
      const int nn1 = nodebase + 2;
      aN = *(const int4*)&pbase[(size_t)nn1 * PLEN];
      bN = *(const int4*)&pbase[(size_t)(nn1 + 1) * PLEN];
    }
    WAITV(2);                                  // idx(0) ready (idx(1) still in flight)
    ISSUE_ROWS(0, aC, bC);
    sc_a[0] = scales[aC.x]; sc_a[1] = scales[aC.y]; sc_a[2] = scales[aC.z]; sc_a[3] = scales[aC.w];
    sc_b[0] = scales[bC.x]; sc_b[1] = scales[bC.y]; sc_b[2] = scales[bC.z]; sc_b[3] = scales[bC.w];
    // invariant entering loop: outstanding = idx(1)[2] + rows(0)[4] + scales(0)[8] = 14

    #pragma unroll 1
    for (int s = 0; s < 7; ++s) {
      // [1] issue idx(s+2) (wrap keeps vmcnt counts uniform at the tail; dummy is harmless)
      const int nn = nodebase + ((s + 2) & 7) * 2;
      aC = *(const int4*)&pbase[(size_t)nn * PLEN];
      bC = *(const int4*)&pbase[(size_t)(nn + 1) * PLEN];
      // [2] wait idx(s+1): 14 younger ops outstanding
      WAITV(14);
      // [3] issue rows(s+1) + scales(s+1) using idx(s+1)
      ISSUE_ROWS(s + 1, aN, bN);
      sn_a[0] = scales[aN.x]; sn_a[1] = scales[aN.y]; sn_a[2] = scales[aN.z]; sn_a[3] = scales[aN.w];
      sn_b[0] = scales[bN.x]; sn_b[1] = scales[bN.y]; sn_b[2] = scales[bN.z]; sn_b[3] = scales[bN.w];
      // [4] wait rows(s)+scales(s): exactly 14 younger ops (idx(s+2)=2 + stage(s+1)=12)
      WAITV(14);
      // [5] consume stage s from LDS
      CONSUME(s, sc_a, sc_b);
      // rotate
      aN = aC; bN = bC;
      sc_a[0] = sn_a[0]; sc_a[1] = sn_a[1]; sc_a[2] = sn_a[2]; sc_a[3] = sn_a[3];
      sc_b[0] = sn_b[0]; sc_b[1] = sn_b[1]; sc_b[2] = sn_b[2]; sc_b[3] = sn_b[3];
    }
    WAITV(0);                                  // drain final stage (7)
    CONSUME(7, sc_a, sc_b);
  } else {
    // ================= generic fallback (cnt > 4): R3-proven structure =================
    const bool v1 = (g + 4 < cnt);
    float cl1[PLEN];
    #pragma unroll
    for (int l = 0; l < PLEN; ++l) {
      const float w = pweights[e * PLEN + l] * ic;
      cl1[l] = v1 ? w : 0.f;
    }
    if (!v1) p1 = 0;

    #pragma unroll 1
    for (int it = 0; it < 8; ++it) {
      const int nA = nodebase + it * 2;
      const int nB = nA + 1;
      const int4 iA = *(const int4*)&pbase[(size_t)nA * PLEN];
      const int4 iB = *(const int4*)&pbase[(size_t)nB * PLEN];
      const int ia[4] = {iA.x, iA.y, iA.z, iA.w};
      const int ib[4] = {iB.x, iB.y, iB.z, iB.w};
      uint2 fa[4], fb[4];
      float sa[4], sb[4];
      #pragma unroll
      for (int l = 0; l < PLEN; ++l) {
        fa[l] = *(const uint2*)(feats_q + (size_t)ia[l] * HIDDEN + r * 8);
        sa[l] = scales[ia[l]];
      }
      #pragma unroll
      for (int l = 0; l < PLEN; ++l) {
        fb[l] = *(const uint2*)(feats_q + (size_t)ib[l] * HIDDEN + r * 8);
        sb[l] = scales[ib[l]];
      }
      #pragma unroll
      for (int half = 0; half < 2; ++half) {
        const int nn = half ? nB : nA;
        float a[8] = {0.f, 0.f, 0.f, 0.f, 0.f, 0.f, 0.f, 0.f};
        float corr = 0.f;
        #pragma unroll
        for (int l = 0; l < PLEN; ++l) {
          const uint2 f = half ? fb[l] : fa[l];
          const float cs = cl0[l] * (half ? sb[l] : sa[l]);
          corr += cs;
          a[0] += cs * (float)( f.x        & 0xFFu);
          a[1] += cs * (float)((f.x >>  8) & 0xFFu);
          a[2] += cs * (float)((f.x >> 16) & 0xFFu);
          a[3] += cs * (float)( f.x >> 24        );
          a[4] += cs * (float)( f.y        & 0xFFu);
          a[5] += cs * (float)((f.y >>  8) & 0xFFu);
          a[6] += cs * (float)((f.y >> 16) & 0xFFu);
          a[7] += cs * (float)( f.y >> 24        );
        }
        {
          const int4 i2 = *(const int4*)&paths[((size_t)p1 * n_nodes + nn) * PLEN];
          const int i2a[4] = {i2.x, i2.y, i2.z, i2.w};
          #pragma unroll
          for (int l = 0; l < PLEN; ++l) {
            const uint2 f = *(const uint2*)(feats_q + (size_t)i2a[l] * HIDDEN + r * 8);
            const float cs = cl1[l] * scales[i2a[l]];
            corr += cs;
            a[0] += cs * (float)( f.x        & 0xFFu);
            a[1] += cs * (float)((f.x >>  8) & 0xFFu);
            a[2] += cs * (float)((f.x >> 16) & 0xFFu);
            a[3] += cs * (float)( f.x >> 24        );
            a[4] += cs * (float)( f.y        & 0xFFu);
            a[5] += cs * (float)((f.y >>  8) & 0xFFu);
            a[6] += cs * (float)((f.y >> 16) & 0xFFu);
            a[7] += cs * (float)( f.y >> 24        );
          }
        }
        #pragma unroll
        for (int k = 0; k < 8; ++k) {
          a[k] += __shfl_xor(a[k], 16);
          a[k] += __shfl_xor(a[k], 32);
        }
        corr += __shfl_xor(corr, 16);
        corr += __shfl_xor(corr, 32);
        const float c128 = 128.f * corr;
        if (g == 0) {
          short8 u;
          #pragma unroll
          for (int k = 0; k < 8; ++k) u[k] = (short)f2bf(a[k] - c128);
          *(short8*)&A[(nh + it * 2 + half) * AROW + e * HIDDEN + r * 8] = u;
        }
      }
    }
  }
  __syncthreads();

  // ---- MFMA GEMM: out(32x128) = A(32x256) @ WfcBf^T(256x128) ---- (R0-proven)
  const int q = lane >> 4;
  const int rr = lane & 15;

  floatx4 acc[2][2];
  #pragma unroll
  for (int mt = 0; mt < 2; ++mt)
    #pragma unroll
    for (int jt = 0; jt < 2; ++jt)
      acc[mt][jt] = (floatx4){0.f, 0.f, 0.f, 0.f};

  #pragma unroll
  for (int kk = 0; kk < 8; ++kk) {
    short8 af[2];
    #pragma unroll
    for (int mt = 0; mt < 2; ++mt)
      af[mt] = *(const short8*)&A[(mt * 16 + rr) * AROW + kk * 32 + q * 8];

    short8 bfr[2];
    #pragma unroll
    for (int jt = 0; jt < 2; ++jt) {
      const int j = wv * 32 + jt * 16 + rr;                  // output col = Wfc row
      bfr[jt] = *(const short8*)&wfc_bf[(size_t)j * (ETYPES * HIDDEN) + kk * 32 + q * 8];
    }

    #pragma unroll
    for (int mt = 0; mt < 2; ++mt)
      #pragma unroll
      for (int jt = 0; jt < 2; ++jt)
        acc[mt][jt] = __builtin_amdgcn_mfma_f32_16x16x32_bf16(af[mt], bfr[jt], acc[mt][jt], 0, 0, 0);
  }

  #pragma unroll
  for (int mt = 0; mt < 2; ++mt) {
    const int node_base = n0 + mt * 16 + q * 4;
    #pragma unroll
    for (int jt = 0; jt < 2; ++jt) {
      const int j = wv * 32 + jt * 16 + rr;
      #pragma unroll
      for (int reg = 0; reg < 4; ++reg) {
        const int nn = node_base + reg;
        if (nn < n_nodes) out[(size_t)nn * HIDDEN + j] = fmaxf(acc[mt][jt][reg], 0.f);
      }
    }
  }
}

extern "C" void kernel_launch(void* const* d_in, const int* in_sizes, int n_in,
                              void* d_out, int out_size, void* d_ws, size_t ws_size,
                              hipStream_t stream) {
  const float* feats    = (const float*)d_in[0];
  const int*   paths    = (const int*)d_in[1];
  const int*   ptypes   = (const int*)d_in[2];
  const float* pweights = (const float*)d_in[3];
  const float* Wfc      = (const float*)d_in[4];
  float* out = (float*)d_out;

  const int n_nodes = in_sizes[0] / HIDDEN;          // 100000
  const int blocks = (n_nodes + BN - 1) / BN;

  // ws layout: [feats_q u8 N*128][scales f32 N][wfc bf16 128*256]
  char* ws = (char*)d_ws;
  unsigned char* feats_q = (unsigned char*)ws;
  float* scales = (float*)(ws + (size_t)n_nodes * HIDDEN);
  unsigned short* wfc_bf = (unsigned short*)(ws + (size_t)n_nodes * HIDDEN
                                                + (size_t)n_nodes * sizeof(float));

  hipLaunchKernelGGL(cvt_u8, dim3((n_nodes + 7) / 8), dim3(256), 0, stream,
                     feats, feats_q, scales, n_nodes);
  const int wfc4 = in_sizes[4] / 4;                  // 32768/4
  hipLaunchKernelGGL(cvt_bf16, dim3((wfc4 + 255) / 256), dim3(256), 0, stream,
                     Wfc, wfc_bf, wfc4);
  hipLaunchKernelGGL(impeller_fused, dim3(blocks), dim3(256), 0, stream,
                     feats_q, scales, paths, ptypes, pweights, wfc_bf, out, n_nodes);
}

// Round 7
// 182.227 us; speedup vs baseline: 1.4973x; 1.4973x over previous
//
#include <hip/hip_runtime.h>

#define HIDDEN 128
#define P_NUM 8
#define PLEN 4
#define ETYPES 2
#define BN 32                      // nodes per block (100000 = 3125*32, no tail)
#define APAD 8
#define AROW (2*HIDDEN + APAD)     // 264 bf16
#define SENC 2040.0f               // scale code: c = ceil(s*2040), s = c/2040

typedef __attribute__((ext_vector_type(8))) short short8;
typedef __attribute__((ext_vector_type(4))) float floatx4;

__device__ __forceinline__ unsigned short f2bf(float x) {
  unsigned int u = __float_as_uint(x);
  u += 0x7FFFu + ((u >> 16) & 1u);
  return (unsigned short)(u >> 16);
}

// Merged converter (one launch):
//  blocks [0,32): W_fc f32 -> bf16
//  blocks [32,..): feats f32 -> biased u8 with PER-4-ROW-GROUP u8-coded scale.
//  Wave = 1 group (4 rows x 128 dims; lane: row=lane>>4, cols (lane&15)*8..+8).
__global__ __launch_bounds__(256) void cvt_all(
    const float* __restrict__ feats, const float* __restrict__ Wfc,
    unsigned char* __restrict__ feats_q, unsigned char* __restrict__ scale_q,
    unsigned short* __restrict__ wfc_bf, int n_nodes, int wfc4)
{
  const int tid = threadIdx.x;
  if (blockIdx.x < 32) {
    int i = blockIdx.x * 256 + tid;
    if (i < wfc4) {
      float4 f = ((const float4*)Wfc)[i];
      ((ushort4*)wfc_bf)[i] = make_ushort4(f2bf(f.x), f2bf(f.y), f2bf(f.z), f2bf(f.w));
    }
    return;
  }
  const int gid = (blockIdx.x - 32) * 4 + (tid >> 6);   // scale group (4 rows)
  const int lane = tid & 63;
  const int rig = lane >> 4;                            // row in group
  const int c0 = (lane & 15) * 8;
  const int row = gid * 4 + rig;
  if (gid * 4 >= n_nodes) return;
  const int rc = (row < n_nodes) ? row : (n_nodes - 1);
  const float* src = feats + (size_t)rc * HIDDEN + c0;
  float4 v0 = ((const float4*)src)[0];
  float4 v1 = ((const float4*)src)[1];
  float m = fmaxf(fmaxf(fmaxf(fabsf(v0.x), fabsf(v0.y)), fmaxf(fabsf(v0.z), fabsf(v0.w))),
                  fmaxf(fmaxf(fabsf(v1.x), fabsf(v1.y)), fmaxf(fabsf(v1.z), fabsf(v1.w))));
  #pragma unroll
  for (int d = 1; d < 64; d <<= 1) m = fmaxf(m, __shfl_xor(m, d));   // group absmax
  int c = (int)ceilf(m * (SENC / 127.f));
  c = (c < 1) ? 1 : ((c > 255) ? 255 : c);
  const float inv = SENC / (float)c;                    // 1/s', s' = c/SENC >= m/127
  float xs[8] = {v0.x, v0.y, v0.z, v0.w, v1.x, v1.y, v1.z, v1.w};
  unsigned int lo = 0, hi = 0;
  #pragma unroll
  for (int k = 0; k < 8; ++k) {
    int u = (int)rintf(xs[k] * inv) + 128;
    u = (u < 0) ? 0 : ((u > 255) ? 255 : u);
    if (k < 4) lo |= (unsigned)u << (8 * k); else hi |= (unsigned)u << (8 * (k - 4));
  }
  if (row < n_nodes) {
    uint2 pk; pk.x = lo; pk.y = hi;
    *(uint2*)(feats_q + (size_t)row * HIDDEN + c0) = pk;
    if (lane == 0) scale_q[gid] = (unsigned char)c;
  }
}

// Fused: type-specialized-wave gather + in-block MFMA GEMM.
// Rows on the vector path (4 groups x 16 lanes -> 4 lines/instr).
// Scales: u8 codes, per-4-node group, 25 KB table -> K$/L2-resident; fetched via
// readlane + scalar loads so the 3.2M scale reads leave the vector miss queue entirely.
__global__ __launch_bounds__(256, 6) void impeller_fused(
    const unsigned char* __restrict__ feats_q,  // biased u8, N x 128
    const unsigned char* __restrict__ scale_q,  // u8 codes, ceil(N/4)
    const int* __restrict__ paths,
    const int* __restrict__ ptypes,
    const float* __restrict__ pweights,
    const unsigned short* __restrict__ wfc_bf,  // bf16, 128 x 256
    float* __restrict__ out,
    int n_nodes)
{
  __shared__ __align__(16) unsigned short A[BN * AROW];   // 16896 B

  const int tid = threadIdx.x;
  const int n0 = blockIdx.x * BN;
  const int wv = tid >> 6;
  const int lane = tid & 63;
  const int g = lane >> 4;          // group 0..3 (one path slot per group)
  const int r = lane & 15;          // dims [r*8, r*8+8)

  const int e = wv >> 1;            // this wave's edge type
  const int nh = (wv & 1) * 16;     // local node half: nh..nh+15

  // ---- this group's path(s) of type e ----
  int p0 = 0, p1 = 0, cnt = 0;
  #pragma unroll
  for (int p = 0; p < P_NUM; ++p) {
    const int t = ptypes[p];
    if (t == e) { if (cnt == g) p0 = p; if (cnt == g + 4) p1 = p; ++cnt; }
  }
  const bool v0 = (g < cnt);
  const float ic = (cnt > 0) ? 1.f / (float)cnt : 0.f;
  float cl0e[PLEN];                 // coefficient with scale-decode folded in (1/SENC)
  #pragma unroll
  for (int l = 0; l < PLEN; ++l) {
    const float w = pweights[e * PLEN + l] * ic * (1.f / SENC);
    cl0e[l] = v0 ? w : 0.f;
  }
  if (!v0) p0 = 0;

  const int* pbase = paths + (size_t)p0 * n_nodes * PLEN;
  const int nodebase = n0 + nh;
  const unsigned* sq32 = (const unsigned*)scale_q;

  // lane-group select masks (for SGPR->VGPR scale select)
  const bool m0 = (g == 0), m1 = (g == 1), m2 = (g == 2);

  if (cnt <= 4) {
    // ================= fast path (R5-proven structure) =================
    int4 iA = *(const int4*)&pbase[(size_t)nodebase * PLEN];
    int4 iB = *(const int4*)&pbase[(size_t)(nodebase + 1) * PLEN];

    #pragma unroll 1
    for (int it = 0; it < 8; ++it) {
      // prefetch next iteration's indices
      int4 iA_n = iA, iB_n = iB;
      if (it < 7) {
        const int nn = nodebase + (it + 1) * 2;
        iA_n = *(const int4*)&pbase[(size_t)nn * PLEN];
        iB_n = *(const int4*)&pbase[(size_t)(nn + 1) * PLEN];
      }

      const int ia[4] = {iA.x, iA.y, iA.z, iA.w};
      const int ib[4] = {iB.x, iB.y, iB.z, iB.w};

      // ---- scalar-path scale-code fetch: 25 KB table, K$/L2-resident ----
      float cA[PLEN][4], cB[PLEN][4];
      #pragma unroll
      for (int l = 0; l < PLEN; ++l) {
        #pragma unroll
        for (int j = 0; j < 4; ++j) {
          const unsigned gi = ((unsigned)__builtin_amdgcn_readlane(ia[l], 16 * j)) >> 2;
          const unsigned w = sq32[gi >> 2];
          cA[l][j] = (float)((w >> ((gi & 3u) << 3)) & 0xFFu);
        }
      }
      #pragma unroll
      for (int l = 0; l < PLEN; ++l) {
        #pragma unroll
        for (int j = 0; j < 4; ++j) {
          const unsigned gi = ((unsigned)__builtin_amdgcn_readlane(ib[l], 16 * j)) >> 2;
          const unsigned w = sq32[gi >> 2];
          cB[l][j] = (float)((w >> ((gi & 3u) << 3)) & 0xFFu);
        }
      }

      // ---- vector-path row loads: 16 x 8B, 4 lines/instr ----
      uint2 fa[4], fb[4];
      #pragma unroll
      for (int l = 0; l < PLEN; ++l)
        fa[l] = *(const uint2*)(feats_q + (size_t)ia[l] * HIDDEN + r * 8);
      #pragma unroll
      for (int l = 0; l < PLEN; ++l)
        fb[l] = *(const uint2*)(feats_q + (size_t)ib[l] * HIDDEN + r * 8);

      // per-lane scale-code select from the 4 group scalars
      float scA[PLEN], scB[PLEN];
      #pragma unroll
      for (int l = 0; l < PLEN; ++l) {
        scA[l] = m0 ? cA[l][0] : (m1 ? cA[l][1] : (m2 ? cA[l][2] : cA[l][3]));
        scB[l] = m0 ? cB[l][0] : (m1 ? cB[l][1] : (m2 ? cB[l][2] : cB[l][3]));
      }

      #pragma unroll
      for (int half = 0; half < 2; ++half) {
        float a[8] = {0.f, 0.f, 0.f, 0.f, 0.f, 0.f, 0.f, 0.f};
        float corr = 0.f;
        #pragma unroll
        for (int l = 0; l < PLEN; ++l) {
          const uint2 f = half ? fb[l] : fa[l];
          const float cs = cl0e[l] * (half ? scB[l] : scA[l]);
          corr += cs;
          a[0] += cs * (float)( f.x        & 0xFFu);
          a[1] += cs * (float)((f.x >>  8) & 0xFFu);
          a[2] += cs * (float)((f.x >> 16) & 0xFFu);
          a[3] += cs * (float)( f.x >> 24        );
          a[4] += cs * (float)( f.y        & 0xFFu);
          a[5] += cs * (float)((f.y >>  8) & 0xFFu);
          a[6] += cs * (float)((f.y >> 16) & 0xFFu);
          a[7] += cs * (float)( f.y >> 24        );
        }
        #pragma unroll
        for (int k = 0; k < 8; ++k) {
          a[k] += __shfl_xor(a[k], 16);
          a[k] += __shfl_xor(a[k], 32);
        }
        corr += __shfl_xor(corr, 16);
        corr += __shfl_xor(corr, 32);
        const float c128 = 128.f * corr;
        if (g == 0) {
          short8 u;
          #pragma unroll
          for (int k = 0; k < 8; ++k) u[k] = (short)f2bf(a[k] - c128);
          *(short8*)&A[(nh + it * 2 + half) * AROW + e * HIDDEN + r * 8] = u;
        }
      }

      iA = iA_n; iB = iB_n;
    }
  } else {
    // ================= generic fallback (cnt > 4) =================
    const bool v1 = (g + 4 < cnt);
    float cl1e[PLEN];
    #pragma unroll
    for (int l = 0; l < PLEN; ++l) {
      const float w = pweights[e * PLEN + l] * ic * (1.f / SENC);
      cl1e[l] = v1 ? w : 0.f;
    }
    if (!v1) p1 = 0;

    #pragma unroll 1
    for (int it = 0; it < 8; ++it) {
      const int nA = nodebase + it * 2;
      const int nB = nA + 1;
      const int4 iA = *(const int4*)&pbase[(size_t)nA * PLEN];
      const int4 iB = *(const int4*)&pbase[(size_t)nB * PLEN];
      const int ia[4] = {iA.x, iA.y, iA.z, iA.w};
      const int ib[4] = {iB.x, iB.y, iB.z, iB.w};
      uint2 fa[4], fb[4];
      float sa[4], sb[4];
      #pragma unroll
      for (int l = 0; l < PLEN; ++l) {
        fa[l] = *(const uint2*)(feats_q + (size_t)ia[l] * HIDDEN + r * 8);
        sa[l] = (float)scale_q[((unsigned)ia[l]) >> 2];
      }
      #pragma unroll
      for (int l = 0; l < PLEN; ++l) {
        fb[l] = *(const uint2*)(feats_q + (size_t)ib[l] * HIDDEN + r * 8);
        sb[l] = (float)scale_q[((unsigned)ib[l]) >> 2];
      }
      #pragma unroll
      for (int half = 0; half < 2; ++half) {
        const int nn = half ? nB : nA;
        float a[8] = {0.f, 0.f, 0.f, 0.f, 0.f, 0.f, 0.f, 0.f};
        float corr = 0.f;
        #pragma unroll
        for (int l = 0; l < PLEN; ++l) {
          const uint2 f = half ? fb[l] : fa[l];
          const float cs = cl0e[l] * (half ? sb[l] : sa[l]);
          corr += cs;
          a[0] += cs * (float)( f.x        & 0xFFu);
          a[1] += cs * (float)((f.x >>  8) & 0xFFu);
          a[2] += cs * (float)((f.x >> 16) & 0xFFu);
          a[3] += cs * (float)( f.x >> 24        );
          a[4] += cs * (float)( f.y        & 0xFFu);
          a[5] += cs * (float)((f.y >>  8) & 0xFFu);
          a[6] += cs * (float)((f.y >> 16) & 0xFFu);
          a[7] += cs * (float)( f.y >> 24        );
        }
        {
          const int4 i2 = *(const int4*)&paths[((size_t)p1 * n_nodes + nn) * PLEN];
          const int i2a[4] = {i2.x, i2.y, i2.z, i2.w};
          #pragma unroll
          for (int l = 0; l < PLEN; ++l) {
            const uint2 f = *(const uint2*)(feats_q + (size_t)i2a[l] * HIDDEN + r * 8);
            const float cs = cl1e[l] * (float)scale_q[((unsigned)i2a[l]) >> 2];
            corr += cs;
            a[0] += cs * (float)( f.x        & 0xFFu);
            a[1] += cs * (float)((f.x >>  8) & 0xFFu);
            a[2] += cs * (float)((f.x >> 16) & 0xFFu);
            a[3] += cs * (float)( f.x >> 24        );
            a[4] += cs * (float)( f.y        & 0xFFu);
            a[5] += cs * (float)((f.y >>  8) & 0xFFu);
            a[6] += cs * (float)((f.y >> 16) & 0xFFu);
            a[7] += cs * (float)( f.y >> 24        );
          }
        }
        #pragma unroll
        for (int k = 0; k < 8; ++k) {
          a[k] += __shfl_xor(a[k], 16);
          a[k] += __shfl_xor(a[k], 32);
        }
        corr += __shfl_xor(corr, 16);
        corr += __shfl_xor(corr, 32);
        const float c128 = 128.f * corr;
        if (g == 0) {
          short8 u;
          #pragma unroll
          for (int k = 0; k < 8; ++k) u[k] = (short)f2bf(a[k] - c128);
          *(short8*)&A[(nh + it * 2 + half) * AROW + e * HIDDEN + r * 8] = u;
        }
      }
    }
  }
  __syncthreads();

  // ---- MFMA GEMM: out(32x128) = A(32x256) @ WfcBf^T(256x128) ---- (R0-proven)
  const int q = lane >> 4;
  const int rr = lane & 15;

  floatx4 acc[2][2];
  #pragma unroll
  for (int mt = 0; mt < 2; ++mt)
    #pragma unroll
    for (int jt = 0; jt < 2; ++jt)
      acc[mt][jt] = (floatx4){0.f, 0.f, 0.f, 0.f};

  #pragma unroll
  for (int kk = 0; kk < 8; ++kk) {
    short8 af[2];
    #pragma unroll
    for (int mt = 0; mt < 2; ++mt)
      af[mt] = *(const short8*)&A[(mt * 16 + rr) * AROW + kk * 32 + q * 8];

    short8 bfr[2];
    #pragma unroll
    for (int jt = 0; jt < 2; ++jt) {
      const int j = wv * 32 + jt * 16 + rr;                  // output col = Wfc row
      bfr[jt] = *(const short8*)&wfc_bf[(size_t)j * (ETYPES * HIDDEN) + kk * 32 + q * 8];
    }

    #pragma unroll
    for (int mt = 0; mt < 2; ++mt)
      #pragma unroll
      for (int jt = 0; jt < 2; ++jt)
        acc[mt][jt] = __builtin_amdgcn_mfma_f32_16x16x32_bf16(af[mt], bfr[jt], acc[mt][jt], 0, 0, 0);
  }

  #pragma unroll
  for (int mt = 0; mt < 2; ++mt) {
    const int node_base = n0 + mt * 16 + q * 4;
    #pragma unroll
    for (int jt = 0; jt < 2; ++jt) {
      const int j = wv * 32 + jt * 16 + rr;
      #pragma unroll
      for (int reg = 0; reg < 4; ++reg) {
        const int nn = node_base + reg;
        if (nn < n_nodes) out[(size_t)nn * HIDDEN + j] = fmaxf(acc[mt][jt][reg], 0.f);
      }
    }
  }
}

extern "C" void kernel_launch(void* const* d_in, const int* in_sizes, int n_in,
                              void* d_out, int out_size, void* d_ws, size_t ws_size,
                              hipStream_t stream) {
  const float* feats    = (const float*)d_in[0];
  const int*   paths    = (const int*)d_in[1];
  const int*   ptypes   = (const int*)d_in[2];
  const float* pweights = (const float*)d_in[3];
  const float* Wfc      = (const float*)d_in[4];
  float* out = (float*)d_out;

  const int n_nodes = in_sizes[0] / HIDDEN;          // 100000
  const int blocks = (n_nodes + BN - 1) / BN;

  // ws layout: [feats_q u8 N*128][scale_q u8 ceil(N/4) pad16][wfc bf16 128*256]
  char* ws = (char*)d_ws;
  unsigned char* feats_q = (unsigned char*)ws;
  unsigned char* scale_q = (unsigned char*)(ws + (size_t)n_nodes * HIDDEN);
  const size_t sq_bytes = (((size_t)(n_nodes + 3) / 4) + 15) & ~(size_t)15;
  unsigned short* wfc_bf = (unsigned short*)(ws + (size_t)n_nodes * HIDDEN + sq_bytes);

  const int wfc4 = in_sizes[4] / 4;                  // 32768/4
  const int cvt_blocks = 32 + (n_nodes + 15) / 16;
  hipLaunchKernelGGL(cvt_all, dim3(cvt_blocks), dim3(256), 0, stream,
                     feats, Wfc, feats_q, scale_q, wfc_bf, n_nodes, wfc4);
  hipLaunchKernelGGL(impeller_fused, dim3(blocks), dim3(256), 0, stream,
                     feats_q, scale_q, paths, ptypes, pweights, wfc_bf, out, n_nodes);
}